// Round 1
// baseline (1193.046 us; speedup 1.0000x reference)
//
#include <hip/hip_runtime.h>
#include <cstdint>
#include <cstddef>

// ---------------------------------------------------------------------------
// QLoRABigNet: 6 blocks x (linear, relu, linear, relu, linear) + LayerNorm.
// D=1024, BATCH=16384. Weights 4-bit group-quantized (GS=16), LoRA rank 32 on
// layers 0/6/12 (merged into dequantized weight: W' = W + B@A — exact).
// Strategy: dequant all 18 layers to bf16 once per launch, then 18 bf16 MFMA
// GEMMs (m97 structure: 128x128 tile, BK=64, global_load_lds width 16,
// XOR-swizzled LDS), LN kernel per block. h kept in bf16 between layers,
// fp32 accumulation everywhere.
// ---------------------------------------------------------------------------

typedef short  bf16x8 __attribute__((ext_vector_type(8)));   // 8 bf16 (4 VGPRs)
typedef float  f32x4  __attribute__((ext_vector_type(4)));

__device__ __forceinline__ unsigned short f2bf(float f) {
  // round-to-nearest-even float -> bf16 bit pattern
  unsigned int u = __builtin_bit_cast(unsigned int, f);
  u += 0x7FFFu + ((u >> 16) & 1u);
  return (unsigned short)(u >> 16);
}

__device__ __forceinline__ void async_copy16(void* lds, const void* g) {
  // global -> LDS direct copy, 16B per lane. LDS dest is wave-uniform base,
  // lane*16 added by HW.
  __builtin_amdgcn_global_load_lds(
      (const __attribute__((address_space(1))) void*)(uintptr_t)(g),
      (__attribute__((address_space(3))) void*)(unsigned int)(uintptr_t)(lds),
      16, 0, 0);
}

// ---------------------------------------------------------------------------
// Dequant (+ LoRA merge for layers 0/6/12). One thread per group of 16.
// grid: (256, 18), block 256.
// ---------------------------------------------------------------------------
__global__ __launch_bounds__(256) void dequant_kernel(
    const int* __restrict__ wq, const float* __restrict__ wn,
    const float* __restrict__ lora_a, const float* __restrict__ lora_b,
    unsigned short* __restrict__ Wbf) {
  const int l = blockIdx.y;
  const int g = blockIdx.x * 256 + threadIdx.x;       // 0..65535
  const long idx = (long)l * 65536 + g;

  int qi[16];
  const int4* q4 = (const int4*)(wq + idx * 16);
  *(int4*)(qi + 0)  = q4[0];
  *(int4*)(qi + 4)  = q4[1];
  *(int4*)(qi + 8)  = q4[2];
  *(int4*)(qi + 12) = q4[3];
  const float n = wn[idx];
  const float s = 2.0f / 15.0f;

  float v[16];
#pragma unroll
  for (int j = 0; j < 16; ++j) v[j] = ((float)qi[j] * s - 1.0f) * n;

  const int slot = (l == 0) ? 0 : (l == 6) ? 1 : (l == 12) ? 2 : -1;
  if (slot >= 0) {
    const int o  = g >> 6;            // output row
    const int i0 = (g & 63) << 4;     // starting input col of this group
    const float* A = lora_a + slot * 32 * 1024 + i0;  // [32][1024]
    const float* B = lora_b + slot * 1024 * 32 + o * 32;  // [1024][32]
#pragma unroll 4
    for (int r = 0; r < 32; ++r) {
      const float br = B[r];
      const float* ar = A + r * 1024;
#pragma unroll
      for (int j = 0; j < 16; ++j) v[j] = fmaf(br, ar[j], v[j]);
    }
  }

  unsigned short ub[16];
#pragma unroll
  for (int j = 0; j < 16; ++j) ub[j] = f2bf(v[j]);
  uint4* dst = (uint4*)(Wbf + idx * 16);
  dst[0] = *(uint4*)(ub + 0);
  dst[1] = *(uint4*)(ub + 8);
}

// ---------------------------------------------------------------------------
// fp32 -> bf16 conversion for the initial x. 8 elems/thread.
// ---------------------------------------------------------------------------
__global__ __launch_bounds__(256) void cvt_bf16_kernel(
    const float* __restrict__ in, unsigned short* __restrict__ out) {
  const long i = ((long)blockIdx.x * 256 + threadIdx.x) * 8;
  const float4 a = *(const float4*)(in + i);
  const float4 b = *(const float4*)(in + i + 4);
  unsigned short u[8] = {f2bf(a.x), f2bf(a.y), f2bf(a.z), f2bf(a.w),
                         f2bf(b.x), f2bf(b.y), f2bf(b.z), f2bf(b.w)};
  *(uint4*)(out + i) = *(uint4*)u;
}

// ---------------------------------------------------------------------------
// GEMM: out[m][n] = sum_k H[m][k] * W[n][k] + bias[n]
// M=16384, N=1024, K=1024. Tile 128x128, BK=64. 256 threads = 4 waves (2x2),
// each wave does a 64x64 subtile = 4x4 MFMA 16x16x32 accumulators.
// MODE 0: relu, bf16 out. MODE 1: no relu, fp32 out.
// LDS: A tile [128 rows][64 k] then B tile, rows of 8 16B-chunks,
// chunk XOR-swizzled by (row&7) so frag ds_read_b128 is only 2-way aliased.
// ---------------------------------------------------------------------------
template <int MODE>
__global__ __launch_bounds__(256, 3) void gemm_kernel(
    const unsigned short* __restrict__ H,   // [16384][1024] bf16
    const unsigned short* __restrict__ W,   // [1024][1024] bf16 (layer slice)
    const float* __restrict__ bias,         // [1024]
    unsigned short* __restrict__ outb,      // MODE 0
    float* __restrict__ outf) {             // MODE 1
  constexpr int K = 1024;
  constexpr int NN = 1024;

  __shared__ uint4 ldsq[2048];              // 32 KiB: A[0..16K), B[16K..32K)
  char* base = (char*)ldsq;

  const int tid = threadIdx.x;
  const int w   = tid >> 6;                 // wave 0..3
  const int ln  = tid & 63;                 // lane
  const int n0  = (blockIdx.x & 7) * 128;
  const int m0  = (blockIdx.x >> 3) * 128;

  // --- staging setup (global_load_lds, 16B/lane, 4 issues per tile per wave)
  // physical chunk P = (w*4+i)*64 + ln ; row = P/8 ; pc = P%8 = ln&7
  // stored global chunk gc = pc ^ (row&7) = (ln&7) ^ (ln>>3)
  const int gc = (ln & 7) ^ (ln >> 3);
  const unsigned short* gA = H + (size_t)(m0 + w * 32 + (ln >> 3)) * K + gc * 8;
  const unsigned short* gB = W + (size_t)(n0 + w * 32 + (ln >> 3)) * K + gc * 8;
  char* ldsA = base + w * 4096;
  char* ldsB = base + 16384 + w * 4096;

  // --- fragment addressing
  const int quad = ln >> 4;
  const int lrow = ln & 15;
  const int sw   = lrow & 7;
  const int c0   = ((quad)     ^ sw) * 16;  // kk=0 chunk byte offset
  const int c1   = ((quad + 4) ^ sw) * 16;  // kk=1
  const int wm   = (w >> 1) * 64;
  const int wn   = (w & 1) * 64;
  const char* fragA = base + (wm + lrow) * 128;
  const char* fragB = base + 16384 + (wn + lrow) * 128;

  f32x4 acc[4][4];
#pragma unroll
  for (int i = 0; i < 4; ++i)
#pragma unroll
    for (int j = 0; j < 4; ++j) acc[i][j] = (f32x4){0.f, 0.f, 0.f, 0.f};

  for (int kt = 0; kt < 16; ++kt) {
    const unsigned short* pA = gA + kt * 64;
    const unsigned short* pB = gB + kt * 64;
#pragma unroll
    for (int i = 0; i < 4; ++i) {
      async_copy16(ldsA + i * 1024, pA + (size_t)i * 8 * K);
      async_copy16(ldsB + i * 1024, pB + (size_t)i * 8 * K);
    }
    __syncthreads();   // compiler emits vmcnt(0) drain before barrier
#pragma unroll
    for (int kk = 0; kk < 2; ++kk) {
      const int co = kk ? c1 : c0;
      bf16x8 af[4], bg[4];
#pragma unroll
      for (int mt = 0; mt < 4; ++mt)
        af[mt] = *(const bf16x8*)(fragA + mt * 2048 + co);
#pragma unroll
      for (int nt = 0; nt < 4; ++nt)
        bg[nt] = *(const bf16x8*)(fragB + nt * 2048 + co);
#pragma unroll
      for (int mt = 0; mt < 4; ++mt)
#pragma unroll
        for (int nt = 0; nt < 4; ++nt)
          acc[mt][nt] = __builtin_amdgcn_mfma_f32_16x16x32_bf16(
              af[mt], bg[nt], acc[mt][nt], 0, 0, 0);
    }
    __syncthreads();   // protect LDS overwrite by next iteration's staging
  }

  // --- epilogue: C/D layout col=lane&15, row=quad*4+reg
#pragma unroll
  for (int nt = 0; nt < 4; ++nt) {
    const int n = n0 + wn + nt * 16 + lrow;
    const float bs = bias[n];
#pragma unroll
    for (int mt = 0; mt < 4; ++mt) {
      const int mb = m0 + wm + mt * 16 + quad * 4;
      f32x4 v = acc[mt][nt];
#pragma unroll
      for (int r = 0; r < 4; ++r) {
        float o = v[r] + bs;
        if (MODE == 0) {
          o = fmaxf(o, 0.0f);
          outb[(size_t)(mb + r) * NN + n] = f2bf(o);
        } else {
          outf[(size_t)(mb + r) * NN + n] = o;
        }
      }
    }
  }
}

// ---------------------------------------------------------------------------
// LayerNorm over rows of 1024. One block (256 thr) per row, 4 elems/thread.
// Writes bf16 h for next block; optionally fp32 (final output). Safe in-place
// (each thread holds its 4 values in regs before any write).
// ---------------------------------------------------------------------------
__global__ __launch_bounds__(256) void ln_kernel(
    const float* __restrict__ in, const float* __restrict__ lnw,
    const float* __restrict__ lnb, unsigned short* __restrict__ outb,
    float* __restrict__ outf, int wf32) {
  const int row = blockIdx.x;
  const int t = threadIdx.x;
  const float4 v = *(const float4*)(in + (size_t)row * 1024 + t * 4);
  float s = v.x + v.y + v.z + v.w;
  float q = v.x * v.x + v.y * v.y + v.z * v.z + v.w * v.w;
#pragma unroll
  for (int off = 32; off; off >>= 1) {
    s += __shfl_down(s, off);
    q += __shfl_down(q, off);
  }
  __shared__ float red[8];
  if ((t & 63) == 0) { red[(t >> 6) * 2] = s; red[(t >> 6) * 2 + 1] = q; }
  __syncthreads();
  s = red[0] + red[2] + red[4] + red[6];
  q = red[1] + red[3] + red[5] + red[7];
  const float mu = s * (1.0f / 1024.0f);
  const float var = q * (1.0f / 1024.0f) - mu * mu;
  const float rs = rsqrtf(var + 1e-5f);
  const float4 w4 = *(const float4*)(lnw + t * 4);
  const float4 b4 = *(const float4*)(lnb + t * 4);
  const float y0 = (v.x - mu) * rs * w4.x + b4.x;
  const float y1 = (v.y - mu) * rs * w4.y + b4.y;
  const float y2 = (v.z - mu) * rs * w4.z + b4.z;
  const float y3 = (v.w - mu) * rs * w4.w + b4.w;
  unsigned short u[4] = {f2bf(y0), f2bf(y1), f2bf(y2), f2bf(y3)};
  *(ushort4*)(outb + (size_t)row * 1024 + t * 4) = *(ushort4*)u;
  if (wf32) {
    float4 y = make_float4(y0, y1, y2, y3);
    *(float4*)(outf + (size_t)row * 1024 + t * 4) = y;
  }
}

// ---------------------------------------------------------------------------
extern "C" void kernel_launch(void* const* d_in, const int* in_sizes, int n_in,
                              void* d_out, int out_size, void* d_ws, size_t ws_size,
                              hipStream_t stream) {
  const float* x    = (const float*)d_in[0];
  const int*   wq   = (const int*)d_in[1];
  const float* wn   = (const float*)d_in[2];
  const float* bias = (const float*)d_in[3];
  const float* la   = (const float*)d_in[4];
  const float* lb   = (const float*)d_in[5];
  const float* lnw  = (const float*)d_in[6];
  const float* lnb  = (const float*)d_in[7];
  float* out = (float*)d_out;

  char* ws = (char*)d_ws;
  unsigned short* Wbf = (unsigned short*)ws;                         // 37,748,736 B
  unsigned short* hA  = (unsigned short*)(ws + 37748736);            // 33,554,432 B
  unsigned short* hB  = (unsigned short*)(ws + 37748736 + 33554432); // 33,554,432 B
  // total ws use: 100 MiB. d_out (64 MB fp32) doubles as pre-LN scratch.

  dequant_kernel<<<dim3(256, 18), 256, 0, stream>>>(wq, wn, la, lb, Wbf);
  cvt_bf16_kernel<<<8192, 256, 0, stream>>>(x, hA);

  for (int blk = 0; blk < 6; ++blk) {
    const int l = blk * 3;
    // pos 0: hA -> hB (relu)
    gemm_kernel<0><<<1024, 256, 0, stream>>>(
        hA, Wbf + (size_t)l * 1048576, bias + l * 1024, hB, nullptr);
    // pos 1: hB -> hA (relu)
    gemm_kernel<0><<<1024, 256, 0, stream>>>(
        hB, Wbf + (size_t)(l + 1) * 1048576, bias + (l + 1) * 1024, hA, nullptr);
    // pos 2: hA -> d_out (fp32, no relu)
    gemm_kernel<1><<<1024, 256, 0, stream>>>(
        hA, Wbf + (size_t)(l + 2) * 1048576, bias + (l + 2) * 1024, nullptr, out);
    // LN: d_out -> hA (bf16); final block also writes fp32 d_out in place
    ln_kernel<<<16384, 256, 0, stream>>>(
        out, lnw + blk * 1024, lnb + blk * 1024, hA, out, blk == 5 ? 1 : 0);
  }
}

// Round 2
// 1170.289 us; speedup vs baseline: 1.0194x; 1.0194x over previous
//
#include <hip/hip_runtime.h>
#include <cstdint>
#include <cstddef>

// ---------------------------------------------------------------------------
// QLoRABigNet: 6 blocks x (linear, relu, linear, relu, linear) + LayerNorm.
// D=1024, BATCH=16384. 4-bit group-quant weights (GS=16), LoRA rank 32 merged
// exactly into dequantized W (W' = W + B@A). 18 bf16 MFMA GEMMs.
// R2 changes: (1) dequant rewritten fully-coalesced (4 thr/group);
// (2) GEMM __launch_bounds__(256,4): all 1024 blocks co-resident, no tail;
// (3) LN row-per-wave, shuffle-only reduction.
// ---------------------------------------------------------------------------

typedef short  bf16x8 __attribute__((ext_vector_type(8)));   // 8 bf16 (4 VGPRs)
typedef float  f32x4  __attribute__((ext_vector_type(4)));

__device__ __forceinline__ unsigned short f2bf(float f) {
  unsigned int u = __builtin_bit_cast(unsigned int, f);
  u += 0x7FFFu + ((u >> 16) & 1u);
  return (unsigned short)(u >> 16);
}

__device__ __forceinline__ void async_copy16(void* lds, const void* g) {
  __builtin_amdgcn_global_load_lds(
      (const __attribute__((address_space(1))) void*)(uintptr_t)(g),
      (__attribute__((address_space(3))) void*)(unsigned int)(uintptr_t)(lds),
      16, 0, 0);
}

// ---------------------------------------------------------------------------
// Dequant (+ LoRA merge). One thread per int4 (4 codes) — fully coalesced:
// lane i loads 16B at base+i*16, stores 8B bf16 at base+i*8.
// grid: (1024, 18), block 256.
// ---------------------------------------------------------------------------
__global__ __launch_bounds__(256) void dequant_kernel(
    const int* __restrict__ wq, const float* __restrict__ wn,
    const float* __restrict__ lora_a, const float* __restrict__ lora_b,
    unsigned short* __restrict__ Wbf) {
  const int l  = blockIdx.y;
  const int gt = blockIdx.x * 256 + threadIdx.x;      // 0..262143
  const long e0   = (long)gt * 4;                     // element idx in layer
  const long base = (long)l * 1048576;

  const int4 q = *(const int4*)(wq + base + e0);
  const float n = wn[l * 65536 + (gt >> 2)];          // 4 codes share a group
  const float s = 2.0f / 15.0f;
  float v0 = ((float)q.x * s - 1.0f) * n;
  float v1 = ((float)q.y * s - 1.0f) * n;
  float v2 = ((float)q.z * s - 1.0f) * n;
  float v3 = ((float)q.w * s - 1.0f) * n;

  const int slot = (l == 0) ? 0 : (l == 6) ? 1 : (l == 12) ? 2 : -1;
  if (slot >= 0) {
    const int o  = (int)(e0 >> 10);                   // out row (block-uniform)
    const int i0 = (int)(e0 & 1023);                  // in col
    const float* A = lora_a + slot * 32768 + i0;      // [32][1024]
    const float* B = lora_b + slot * 32768 + o * 32;  // [1024][32]
#pragma unroll 8
    for (int r = 0; r < 32; ++r) {
      const float4 a4 = *(const float4*)(A + r * 1024);
      const float br = B[r];
      v0 = fmaf(br, a4.x, v0);
      v1 = fmaf(br, a4.y, v1);
      v2 = fmaf(br, a4.z, v2);
      v3 = fmaf(br, a4.w, v3);
    }
  }

  unsigned short u[4] = {f2bf(v0), f2bf(v1), f2bf(v2), f2bf(v3)};
  *(uint2*)(Wbf + base + e0) = *(uint2*)u;
}

// ---------------------------------------------------------------------------
// fp32 -> bf16 conversion for the initial x. 8 elems/thread.
// ---------------------------------------------------------------------------
__global__ __launch_bounds__(256) void cvt_bf16_kernel(
    const float* __restrict__ in, unsigned short* __restrict__ out) {
  const long i = ((long)blockIdx.x * 256 + threadIdx.x) * 8;
  const float4 a = *(const float4*)(in + i);
  const float4 b = *(const float4*)(in + i + 4);
  unsigned short u[8] = {f2bf(a.x), f2bf(a.y), f2bf(a.z), f2bf(a.w),
                         f2bf(b.x), f2bf(b.y), f2bf(b.z), f2bf(b.w)};
  *(uint4*)(out + i) = *(uint4*)u;
}

// ---------------------------------------------------------------------------
// GEMM: out[m][n] = sum_k H[m][k] * W[n][k] + bias[n]
// M=16384, N=1024, K=1024. Tile 128x128, BK=64, 4 waves (2x2), 4x4 MFMA
// 16x16x32 acc/wave. __launch_bounds__(256,4): 4 blocks/CU -> all 1024
// blocks co-resident (zero dispatch tail); LDS 4x32KB=128KB/CU <= 160KB.
// MODE 0: relu, bf16 out. MODE 1: no relu, fp32 out.
// ---------------------------------------------------------------------------
template <int MODE>
__global__ __launch_bounds__(256, 4) void gemm_kernel(
    const unsigned short* __restrict__ H,   // [16384][1024] bf16
    const unsigned short* __restrict__ W,   // [1024][1024] bf16 (layer slice)
    const float* __restrict__ bias,         // [1024]
    unsigned short* __restrict__ outb,      // MODE 0
    float* __restrict__ outf) {             // MODE 1
  constexpr int K = 1024;
  constexpr int NN = 1024;

  __shared__ uint4 ldsq[2048];              // 32 KiB: A[0..16K), B[16K..32K)
  char* base = (char*)ldsq;

  const int tid = threadIdx.x;
  const int w   = tid >> 6;
  const int ln  = tid & 63;
  const int n0  = (blockIdx.x & 7) * 128;
  const int m0  = (blockIdx.x >> 3) * 128;

  // staging: physical chunk P = (w*4+i)*64 + ln; row = P/8; pc = ln&7
  // stored global chunk gc = pc ^ (row&7) = (ln&7) ^ (ln>>3)
  const int gc = (ln & 7) ^ (ln >> 3);
  const unsigned short* gA = H + (size_t)(m0 + w * 32 + (ln >> 3)) * K + gc * 8;
  const unsigned short* gB = W + (size_t)(n0 + w * 32 + (ln >> 3)) * K + gc * 8;
  char* ldsA = base + w * 4096;
  char* ldsB = base + 16384 + w * 4096;

  const int quad = ln >> 4;
  const int lrow = ln & 15;
  const int sw   = lrow & 7;
  const int c0   = ((quad)     ^ sw) * 16;
  const int c1   = ((quad + 4) ^ sw) * 16;
  const int wm   = (w >> 1) * 64;
  const int wn   = (w & 1) * 64;
  const char* fragA = base + (wm + lrow) * 128;
  const char* fragB = base + 16384 + (wn + lrow) * 128;

  f32x4 acc[4][4];
#pragma unroll
  for (int i = 0; i < 4; ++i)
#pragma unroll
    for (int j = 0; j < 4; ++j) acc[i][j] = (f32x4){0.f, 0.f, 0.f, 0.f};

  for (int kt = 0; kt < 16; ++kt) {
    const unsigned short* pA = gA + kt * 64;
    const unsigned short* pB = gB + kt * 64;
#pragma unroll
    for (int i = 0; i < 4; ++i) {
      async_copy16(ldsA + i * 1024, pA + (size_t)i * 8 * K);
      async_copy16(ldsB + i * 1024, pB + (size_t)i * 8 * K);
    }
    __syncthreads();
#pragma unroll
    for (int kk = 0; kk < 2; ++kk) {
      const int co = kk ? c1 : c0;
      bf16x8 af[4], bg[4];
#pragma unroll
      for (int mt = 0; mt < 4; ++mt)
        af[mt] = *(const bf16x8*)(fragA + mt * 2048 + co);
#pragma unroll
      for (int nt = 0; nt < 4; ++nt)
        bg[nt] = *(const bf16x8*)(fragB + nt * 2048 + co);
#pragma unroll
      for (int mt = 0; mt < 4; ++mt)
#pragma unroll
        for (int nt = 0; nt < 4; ++nt)
          acc[mt][nt] = __builtin_amdgcn_mfma_f32_16x16x32_bf16(
              af[mt], bg[nt], acc[mt][nt], 0, 0, 0);
    }
    __syncthreads();
  }

  // epilogue: C/D layout col=lane&15, row=quad*4+reg
#pragma unroll
  for (int nt = 0; nt < 4; ++nt) {
    const int n = n0 + wn + nt * 16 + lrow;
    const float bs = bias[n];
#pragma unroll
    for (int mt = 0; mt < 4; ++mt) {
      const int mb = m0 + wm + mt * 16 + quad * 4;
      f32x4 v = acc[mt][nt];
#pragma unroll
      for (int r = 0; r < 4; ++r) {
        float o = v[r] + bs;
        if (MODE == 0) {
          o = fmaxf(o, 0.0f);
          outb[(size_t)(mb + r) * NN + n] = f2bf(o);
        } else {
          outf[(size_t)(mb + r) * NN + n] = o;
        }
      }
    }
  }
}

// ---------------------------------------------------------------------------
// LayerNorm over rows of 1024. One WAVE per row (4 rows/block), shuffle-only
// reduction. grid 4096, block 256.
// ---------------------------------------------------------------------------
__global__ __launch_bounds__(256) void ln_kernel(
    const float* __restrict__ in, const float* __restrict__ lnw,
    const float* __restrict__ lnb, unsigned short* __restrict__ outb,
    float* __restrict__ outf, int wf32) {
  const int wv = threadIdx.x >> 6;
  const int ln = threadIdx.x & 63;
  const int row = blockIdx.x * 4 + wv;
  const float* p = in + (size_t)row * 1024;

  float4 v[4];
  float s = 0.f, q = 0.f;
#pragma unroll
  for (int c = 0; c < 4; ++c) {
    v[c] = *(const float4*)(p + c * 256 + ln * 4);
    s += v[c].x + v[c].y + v[c].z + v[c].w;
    q += v[c].x * v[c].x + v[c].y * v[c].y + v[c].z * v[c].z + v[c].w * v[c].w;
  }
#pragma unroll
  for (int off = 32; off; off >>= 1) {
    s += __shfl_xor(s, off);
    q += __shfl_xor(q, off);
  }
  const float mu  = s * (1.0f / 1024.0f);
  const float var = q * (1.0f / 1024.0f) - mu * mu;
  const float rs  = rsqrtf(var + 1e-5f);

#pragma unroll
  for (int c = 0; c < 4; ++c) {
    const int col = c * 256 + ln * 4;
    const float4 w4 = *(const float4*)(lnw + col);
    const float4 b4 = *(const float4*)(lnb + col);
    const float y0 = (v[c].x - mu) * rs * w4.x + b4.x;
    const float y1 = (v[c].y - mu) * rs * w4.y + b4.y;
    const float y2 = (v[c].z - mu) * rs * w4.z + b4.z;
    const float y3 = (v[c].w - mu) * rs * w4.w + b4.w;
    unsigned short u[4] = {f2bf(y0), f2bf(y1), f2bf(y2), f2bf(y3)};
    *(ushort4*)(outb + (size_t)row * 1024 + col) = *(ushort4*)u;
    if (wf32) {
      float4 y = make_float4(y0, y1, y2, y3);
      *(float4*)(outf + (size_t)row * 1024 + col) = y;
    }
  }
}

// ---------------------------------------------------------------------------
extern "C" void kernel_launch(void* const* d_in, const int* in_sizes, int n_in,
                              void* d_out, int out_size, void* d_ws, size_t ws_size,
                              hipStream_t stream) {
  const int*   wq   = (const int*)d_in[1];
  const float* wn   = (const float*)d_in[2];
  const float* bias = (const float*)d_in[3];
  const float* la   = (const float*)d_in[4];
  const float* lb   = (const float*)d_in[5];
  const float* lnw  = (const float*)d_in[6];
  const float* lnb  = (const float*)d_in[7];
  const float* x    = (const float*)d_in[0];
  float* out = (float*)d_out;

  char* ws = (char*)d_ws;
  unsigned short* Wbf = (unsigned short*)ws;                         // 37.75 MB
  unsigned short* hA  = (unsigned short*)(ws + 37748736);            // 32 MB
  unsigned short* hB  = (unsigned short*)(ws + 37748736 + 33554432); // 32 MB

  dequant_kernel<<<dim3(1024, 18), 256, 0, stream>>>(wq, wn, la, lb, Wbf);
  cvt_bf16_kernel<<<8192, 256, 0, stream>>>(x, hA);

  for (int blk = 0; blk < 6; ++blk) {
    const int l = blk * 3;
    gemm_kernel<0><<<1024, 256, 0, stream>>>(
        hA, Wbf + (size_t)l * 1048576, bias + l * 1024, hB, nullptr);
    gemm_kernel<0><<<1024, 256, 0, stream>>>(
        hB, Wbf + (size_t)(l + 1) * 1048576, bias + (l + 1) * 1024, hA, nullptr);
    gemm_kernel<1><<<1024, 256, 0, stream>>>(
        hA, Wbf + (size_t)(l + 2) * 1048576, bias + (l + 2) * 1024, nullptr, out);
    ln_kernel<<<4096, 256, 0, stream>>>(
        out, lnw + blk * 1024, lnb + blk * 1024, hA, out, blk == 5 ? 1 : 0);
  }
}

// Round 3
// 978.896 us; speedup vs baseline: 1.2188x; 1.1955x over previous
//
#include <hip/hip_runtime.h>
#include <cstdint>
#include <cstddef>

// ---------------------------------------------------------------------------
// QLoRABigNet: 6 blocks x (linear, relu, linear, relu, linear) + LayerNorm.
// D=1024, BATCH=16384. 4-bit group-quant weights (GS=16), LoRA rank 32 merged
// exactly into dequantized W (W' = W + B@A). 18 bf16 MFMA GEMMs.
// R3 change: XCD-aware block swizzle in GEMM. Dispatch round-robins block i ->
// XCD i%8; old mapping put the 8 n-tiles sharing an H-strip on 8 different
// XCDs (8x H fetch at L2 boundary, FETCH_SIZE 132MB vs 34MB ideal). New
// mapping keeps them on one XCD: m_tile = (b&7)*16 + (b>>6), n_tile=(b>>3)&7.
// ---------------------------------------------------------------------------

typedef short  bf16x8 __attribute__((ext_vector_type(8)));   // 8 bf16 (4 VGPRs)
typedef float  f32x4  __attribute__((ext_vector_type(4)));

__device__ __forceinline__ unsigned short f2bf(float f) {
  unsigned int u = __builtin_bit_cast(unsigned int, f);
  u += 0x7FFFu + ((u >> 16) & 1u);
  return (unsigned short)(u >> 16);
}

__device__ __forceinline__ void async_copy16(void* lds, const void* g) {
  __builtin_amdgcn_global_load_lds(
      (const __attribute__((address_space(1))) void*)(uintptr_t)(g),
      (__attribute__((address_space(3))) void*)(unsigned int)(uintptr_t)(lds),
      16, 0, 0);
}

// ---------------------------------------------------------------------------
// Dequant (+ LoRA merge). One thread per int4 (4 codes) — fully coalesced.
// grid: (1024, 18), block 256.
// ---------------------------------------------------------------------------
__global__ __launch_bounds__(256) void dequant_kernel(
    const int* __restrict__ wq, const float* __restrict__ wn,
    const float* __restrict__ lora_a, const float* __restrict__ lora_b,
    unsigned short* __restrict__ Wbf) {
  const int l  = blockIdx.y;
  const int gt = blockIdx.x * 256 + threadIdx.x;      // 0..262143
  const long e0   = (long)gt * 4;
  const long base = (long)l * 1048576;

  const int4 q = *(const int4*)(wq + base + e0);
  const float n = wn[l * 65536 + (gt >> 2)];
  const float s = 2.0f / 15.0f;
  float v0 = ((float)q.x * s - 1.0f) * n;
  float v1 = ((float)q.y * s - 1.0f) * n;
  float v2 = ((float)q.z * s - 1.0f) * n;
  float v3 = ((float)q.w * s - 1.0f) * n;

  const int slot = (l == 0) ? 0 : (l == 6) ? 1 : (l == 12) ? 2 : -1;
  if (slot >= 0) {
    const int o  = (int)(e0 >> 10);                   // out row (block-uniform)
    const int i0 = (int)(e0 & 1023);                  // in col
    const float* A = lora_a + slot * 32768 + i0;      // [32][1024]
    const float* B = lora_b + slot * 32768 + o * 32;  // [1024][32]
#pragma unroll 8
    for (int r = 0; r < 32; ++r) {
      const float4 a4 = *(const float4*)(A + r * 1024);
      const float br = B[r];
      v0 = fmaf(br, a4.x, v0);
      v1 = fmaf(br, a4.y, v1);
      v2 = fmaf(br, a4.z, v2);
      v3 = fmaf(br, a4.w, v3);
    }
  }

  unsigned short u[4] = {f2bf(v0), f2bf(v1), f2bf(v2), f2bf(v3)};
  *(uint2*)(Wbf + base + e0) = *(uint2*)u;
}

// ---------------------------------------------------------------------------
// fp32 -> bf16 conversion for the initial x. 8 elems/thread.
// ---------------------------------------------------------------------------
__global__ __launch_bounds__(256) void cvt_bf16_kernel(
    const float* __restrict__ in, unsigned short* __restrict__ out) {
  const long i = ((long)blockIdx.x * 256 + threadIdx.x) * 8;
  const float4 a = *(const float4*)(in + i);
  const float4 b = *(const float4*)(in + i + 4);
  unsigned short u[8] = {f2bf(a.x), f2bf(a.y), f2bf(a.z), f2bf(a.w),
                         f2bf(b.x), f2bf(b.y), f2bf(b.z), f2bf(b.w)};
  *(uint4*)(out + i) = *(uint4*)u;
}

// ---------------------------------------------------------------------------
// GEMM: out[m][n] = sum_k H[m][k] * W[n][k] + bias[n]
// M=16384, N=1024, K=1024. Tile 128x128, BK=64, 4 waves (2x2), 4x4 MFMA
// 16x16x32 acc/wave, 4 blocks/CU (all 1024 blocks co-resident, zero tail).
// XCD-aware swizzle: all 8 n-tiles of an m-tile on one XCD.
// MODE 0: relu, bf16 out. MODE 1: no relu, fp32 out.
// ---------------------------------------------------------------------------
template <int MODE>
__global__ __launch_bounds__(256, 4) void gemm_kernel(
    const unsigned short* __restrict__ H,   // [16384][1024] bf16
    const unsigned short* __restrict__ W,   // [1024][1024] bf16 (layer slice)
    const float* __restrict__ bias,         // [1024]
    unsigned short* __restrict__ outb,      // MODE 0
    float* __restrict__ outf) {             // MODE 1
  constexpr int K = 1024;
  constexpr int NN = 1024;

  __shared__ uint4 ldsq[2048];              // 32 KiB: A[0..16K), B[16K..32K)
  char* base = (char*)ldsq;

  const int tid = threadIdx.x;
  const int w   = tid >> 6;
  const int ln  = tid & 63;
  // XCD-aware swizzle: block b -> XCD b%8. Keep the 8 n-tiles of each m-tile
  // on one XCD so the H strip is fetched into that XCD's L2 once.
  const int b    = blockIdx.x;
  const int m0   = ((b & 7) * 16 + (b >> 6)) * 128;
  const int n0   = ((b >> 3) & 7) * 128;

  // staging: physical chunk P = (w*4+i)*64 + ln; row = P/8; pc = ln&7
  // stored global chunk gc = pc ^ (row&7) = (ln&7) ^ (ln>>3)
  const int gc = (ln & 7) ^ (ln >> 3);
  const unsigned short* gA = H + (size_t)(m0 + w * 32 + (ln >> 3)) * K + gc * 8;
  const unsigned short* gB = W + (size_t)(n0 + w * 32 + (ln >> 3)) * K + gc * 8;
  char* ldsA = base + w * 4096;
  char* ldsB = base + 16384 + w * 4096;

  const int quad = ln >> 4;
  const int lrow = ln & 15;
  const int sw   = lrow & 7;
  const int c0   = ((quad)     ^ sw) * 16;
  const int c1   = ((quad + 4) ^ sw) * 16;
  const int wm   = (w >> 1) * 64;
  const int wn   = (w & 1) * 64;
  const char* fragA = base + (wm + lrow) * 128;
  const char* fragB = base + 16384 + (wn + lrow) * 128;

  f32x4 acc[4][4];
#pragma unroll
  for (int i = 0; i < 4; ++i)
#pragma unroll
    for (int j = 0; j < 4; ++j) acc[i][j] = (f32x4){0.f, 0.f, 0.f, 0.f};

  for (int kt = 0; kt < 16; ++kt) {
    const unsigned short* pA = gA + kt * 64;
    const unsigned short* pB = gB + kt * 64;
#pragma unroll
    for (int i = 0; i < 4; ++i) {
      async_copy16(ldsA + i * 1024, pA + (size_t)i * 8 * K);
      async_copy16(ldsB + i * 1024, pB + (size_t)i * 8 * K);
    }
    __syncthreads();
#pragma unroll
    for (int kk = 0; kk < 2; ++kk) {
      const int co = kk ? c1 : c0;
      bf16x8 af[4], bg[4];
#pragma unroll
      for (int mt = 0; mt < 4; ++mt)
        af[mt] = *(const bf16x8*)(fragA + mt * 2048 + co);
#pragma unroll
      for (int nt = 0; nt < 4; ++nt)
        bg[nt] = *(const bf16x8*)(fragB + nt * 2048 + co);
#pragma unroll
      for (int mt = 0; mt < 4; ++mt)
#pragma unroll
        for (int nt = 0; nt < 4; ++nt)
          acc[mt][nt] = __builtin_amdgcn_mfma_f32_16x16x32_bf16(
              af[mt], bg[nt], acc[mt][nt], 0, 0, 0);
    }
    __syncthreads();
  }

  // epilogue: C/D layout col=lane&15, row=quad*4+reg
#pragma unroll
  for (int nt = 0; nt < 4; ++nt) {
    const int n = n0 + wn + nt * 16 + lrow;
    const float bs = bias[n];
#pragma unroll
    for (int mt = 0; mt < 4; ++mt) {
      const int mb = m0 + wm + mt * 16 + quad * 4;
      f32x4 v = acc[mt][nt];
#pragma unroll
      for (int r = 0; r < 4; ++r) {
        float o = v[r] + bs;
        if (MODE == 0) {
          o = fmaxf(o, 0.0f);
          outb[(size_t)(mb + r) * NN + n] = f2bf(o);
        } else {
          outf[(size_t)(mb + r) * NN + n] = o;
        }
      }
    }
  }
}

// ---------------------------------------------------------------------------
// LayerNorm over rows of 1024. One WAVE per row (4 rows/block), shuffle-only
// reduction. grid 4096, block 256.
// ---------------------------------------------------------------------------
__global__ __launch_bounds__(256) void ln_kernel(
    const float* __restrict__ in, const float* __restrict__ lnw,
    const float* __restrict__ lnb, unsigned short* __restrict__ outb,
    float* __restrict__ outf, int wf32) {
  const int wv = threadIdx.x >> 6;
  const int ln = threadIdx.x & 63;
  const int row = blockIdx.x * 4 + wv;
  const float* p = in + (size_t)row * 1024;

  float4 v[4];
  float s = 0.f, q = 0.f;
#pragma unroll
  for (int c = 0; c < 4; ++c) {
    v[c] = *(const float4*)(p + c * 256 + ln * 4);
    s += v[c].x + v[c].y + v[c].z + v[c].w;
    q += v[c].x * v[c].x + v[c].y * v[c].y + v[c].z * v[c].z + v[c].w * v[c].w;
  }
#pragma unroll
  for (int off = 32; off; off >>= 1) {
    s += __shfl_xor(s, off);
    q += __shfl_xor(q, off);
  }
  const float mu  = s * (1.0f / 1024.0f);
  const float var = q * (1.0f / 1024.0f) - mu * mu;
  const float rs  = rsqrtf(var + 1e-5f);

#pragma unroll
  for (int c = 0; c < 4; ++c) {
    const int col = c * 256 + ln * 4;
    const float4 w4 = *(const float4*)(lnw + col);
    const float4 b4 = *(const float4*)(lnb + col);
    const float y0 = (v[c].x - mu) * rs * w4.x + b4.x;
    const float y1 = (v[c].y - mu) * rs * w4.y + b4.y;
    const float y2 = (v[c].z - mu) * rs * w4.z + b4.z;
    const float y3 = (v[c].w - mu) * rs * w4.w + b4.w;
    unsigned short u[4] = {f2bf(y0), f2bf(y1), f2bf(y2), f2bf(y3)};
    *(ushort4*)(outb + (size_t)row * 1024 + col) = *(ushort4*)u;
    if (wf32) {
      float4 y = make_float4(y0, y1, y2, y3);
      *(float4*)(outf + (size_t)row * 1024 + col) = y;
    }
  }
}

// ---------------------------------------------------------------------------
extern "C" void kernel_launch(void* const* d_in, const int* in_sizes, int n_in,
                              void* d_out, int out_size, void* d_ws, size_t ws_size,
                              hipStream_t stream) {
  const float* x    = (const float*)d_in[0];
  const int*   wq   = (const int*)d_in[1];
  const float* wn   = (const float*)d_in[2];
  const float* bias = (const float*)d_in[3];
  const float* la   = (const float*)d_in[4];
  const float* lb   = (const float*)d_in[5];
  const float* lnw  = (const float*)d_in[6];
  const float* lnb  = (const float*)d_in[7];
  float* out = (float*)d_out;

  char* ws = (char*)d_ws;
  unsigned short* Wbf = (unsigned short*)ws;                         // 37.75 MB
  unsigned short* hA  = (unsigned short*)(ws + 37748736);            // 32 MB
  unsigned short* hB  = (unsigned short*)(ws + 37748736 + 33554432); // 32 MB

  dequant_kernel<<<dim3(1024, 18), 256, 0, stream>>>(wq, wn, la, lb, Wbf);
  cvt_bf16_kernel<<<8192, 256, 0, stream>>>(x, hA);

  for (int blk = 0; blk < 6; ++blk) {
    const int l = blk * 3;
    gemm_kernel<0><<<1024, 256, 0, stream>>>(
        hA, Wbf + (size_t)l * 1048576, bias + l * 1024, hB, nullptr);
    gemm_kernel<0><<<1024, 256, 0, stream>>>(
        hB, Wbf + (size_t)(l + 1) * 1048576, bias + (l + 1) * 1024, hA, nullptr);
    gemm_kernel<1><<<1024, 256, 0, stream>>>(
        hA, Wbf + (size_t)(l + 2) * 1048576, bias + (l + 2) * 1024, nullptr, out);
    ln_kernel<<<4096, 256, 0, stream>>>(
        out, lnw + blk * 1024, lnb + blk * 1024, hA, out, blk == 5 ? 1 : 0);
  }
}

// Round 4
// 919.091 us; speedup vs baseline: 1.2981x; 1.0651x over previous
//
#include <hip/hip_runtime.h>
#include <cstdint>
#include <cstddef>

// ---------------------------------------------------------------------------
// QLoRABigNet: 6 blocks x (linear, relu, linear, relu, linear) + LayerNorm.
// D=1024, BATCH=16384. 4-bit group-quant weights (GS=16), LoRA rank 32 merged
// exactly into dequantized W (W' = W + B@A). 18 bf16 MFMA GEMMs.
// R4 change: dequant + cvt widened to 4 independent 16B loads/thread.
// R3 counters showed dequant at 1.55 TB/s, VALUBusy 10% — latency-bound with
// only 1 load in flight per thread. 4x MLP should reach the ~19 us floor.
// ---------------------------------------------------------------------------

typedef short  bf16x8 __attribute__((ext_vector_type(8)));   // 8 bf16 (4 VGPRs)
typedef float  f32x4  __attribute__((ext_vector_type(4)));

__device__ __forceinline__ unsigned short f2bf(float f) {
  unsigned int u = __builtin_bit_cast(unsigned int, f);
  u += 0x7FFFu + ((u >> 16) & 1u);
  return (unsigned short)(u >> 16);
}

__device__ __forceinline__ void async_copy16(void* lds, const void* g) {
  __builtin_amdgcn_global_load_lds(
      (const __attribute__((address_space(1))) void*)(uintptr_t)(g),
      (__attribute__((address_space(3))) void*)(unsigned int)(uintptr_t)(lds),
      16, 0, 0);
}

// ---------------------------------------------------------------------------
// Dequant (+ LoRA merge). 4 independent int4 loads per thread (16 elements),
// all streams coalesced. Block covers 4096 contiguous elements of one layer.
// grid: (256, 18), block 256.
// ---------------------------------------------------------------------------
__global__ __launch_bounds__(256) void dequant_kernel(
    const int* __restrict__ wq, const float* __restrict__ wn,
    const float* __restrict__ lora_a, const float* __restrict__ lora_b,
    unsigned short* __restrict__ Wbf) {
  const int l   = blockIdx.y;
  const int t   = threadIdx.x;
  const int blk = blockIdx.x;
  const long base = (long)l * 1048576;
  const float s = 2.0f / 15.0f;

  // 4 independent 16B code loads + 4 independent 4B norm loads
  int4  q[4];
  float nrm[4];
#pragma unroll
  for (int k = 0; k < 4; ++k) {
    const int i4 = blk * 1024 + k * 256 + t;          // int4 index in layer
    q[k]   = *(const int4*)(wq + base + (long)i4 * 4);
    nrm[k] = wn[l * 65536 + (i4 >> 2)];
  }

  float v[4][4];
#pragma unroll
  for (int k = 0; k < 4; ++k) {
    v[k][0] = ((float)q[k].x * s - 1.0f) * nrm[k];
    v[k][1] = ((float)q[k].y * s - 1.0f) * nrm[k];
    v[k][2] = ((float)q[k].z * s - 1.0f) * nrm[k];
    v[k][3] = ((float)q[k].w * s - 1.0f) * nrm[k];
  }

  const int slot = (l == 0) ? 0 : (l == 6) ? 1 : (l == 12) ? 2 : -1;
  if (slot >= 0) {
    // rows o = blk*4 + k (block-uniform per k), cols i0 = t*4 (same for all k)
    const float* A = lora_a + slot * 32768 + t * 4;      // [32][1024]
    const float* B = lora_b + slot * 32768 + blk * 128;  // rows blk*4..+3
#pragma unroll 8
    for (int r = 0; r < 32; ++r) {
      const float4 a4 = *(const float4*)(A + r * 1024);  // shared by all 4 rows
#pragma unroll
      for (int k = 0; k < 4; ++k) {
        const float br = B[k * 32 + r];                  // uniform s_load
        v[k][0] = fmaf(br, a4.x, v[k][0]);
        v[k][1] = fmaf(br, a4.y, v[k][1]);
        v[k][2] = fmaf(br, a4.z, v[k][2]);
        v[k][3] = fmaf(br, a4.w, v[k][3]);
      }
    }
  }

#pragma unroll
  for (int k = 0; k < 4; ++k) {
    unsigned short u[4] = {f2bf(v[k][0]), f2bf(v[k][1]),
                           f2bf(v[k][2]), f2bf(v[k][3])};
    const long e0 = base + ((long)blk * 1024 + k * 256 + t) * 4;
    *(uint2*)(Wbf + e0) = *(uint2*)u;
  }
}

// ---------------------------------------------------------------------------
// fp32 -> bf16 for the initial x. 4 independent float4 loads per thread.
// grid 4096, block 256 (16 elems/thread).
// ---------------------------------------------------------------------------
__global__ __launch_bounds__(256) void cvt_bf16_kernel(
    const float* __restrict__ in, unsigned short* __restrict__ out) {
  const long b0 = (long)blockIdx.x * 4096 + threadIdx.x * 4;
  float4 v[4];
#pragma unroll
  for (int k = 0; k < 4; ++k) v[k] = *(const float4*)(in + b0 + k * 1024);
#pragma unroll
  for (int k = 0; k < 4; ++k) {
    unsigned short u[4] = {f2bf(v[k].x), f2bf(v[k].y), f2bf(v[k].z), f2bf(v[k].w)};
    *(ushort4*)(out + b0 + k * 1024) = *(ushort4*)u;
  }
}

// ---------------------------------------------------------------------------
// GEMM: out[m][n] = sum_k H[m][k] * W[n][k] + bias[n]
// M=16384, N=1024, K=1024. Tile 128x128, BK=64, 4 waves (2x2), 4x4 MFMA
// 16x16x32 acc/wave, 4 blocks/CU (all 1024 blocks co-resident, zero tail).
// XCD-aware swizzle: all 8 n-tiles of an m-tile on one XCD.
// MODE 0: relu, bf16 out. MODE 1: no relu, fp32 out.
// ---------------------------------------------------------------------------
template <int MODE>
__global__ __launch_bounds__(256, 4) void gemm_kernel(
    const unsigned short* __restrict__ H,   // [16384][1024] bf16
    const unsigned short* __restrict__ W,   // [1024][1024] bf16 (layer slice)
    const float* __restrict__ bias,         // [1024]
    unsigned short* __restrict__ outb,      // MODE 0
    float* __restrict__ outf) {             // MODE 1
  constexpr int K = 1024;
  constexpr int NN = 1024;

  __shared__ uint4 ldsq[2048];              // 32 KiB: A[0..16K), B[16K..32K)
  char* base = (char*)ldsq;

  const int tid = threadIdx.x;
  const int w   = tid >> 6;
  const int ln  = tid & 63;
  const int b   = blockIdx.x;
  const int m0  = ((b & 7) * 16 + (b >> 6)) * 128;
  const int n0  = ((b >> 3) & 7) * 128;

  // staging: physical chunk P = (w*4+i)*64 + ln; row = P/8; pc = ln&7
  // stored global chunk gc = pc ^ (row&7) = (ln&7) ^ (ln>>3)
  const int gc = (ln & 7) ^ (ln >> 3);
  const unsigned short* gA = H + (size_t)(m0 + w * 32 + (ln >> 3)) * K + gc * 8;
  const unsigned short* gB = W + (size_t)(n0 + w * 32 + (ln >> 3)) * K + gc * 8;
  char* ldsA = base + w * 4096;
  char* ldsB = base + 16384 + w * 4096;

  const int quad = ln >> 4;
  const int lrow = ln & 15;
  const int sw   = lrow & 7;
  const int c0   = ((quad)     ^ sw) * 16;
  const int c1   = ((quad + 4) ^ sw) * 16;
  const int wm   = (w >> 1) * 64;
  const int wn   = (w & 1) * 64;
  const char* fragA = base + (wm + lrow) * 128;
  const char* fragB = base + 16384 + (wn + lrow) * 128;

  f32x4 acc[4][4];
#pragma unroll
  for (int i = 0; i < 4; ++i)
#pragma unroll
    for (int j = 0; j < 4; ++j) acc[i][j] = (f32x4){0.f, 0.f, 0.f, 0.f};

  for (int kt = 0; kt < 16; ++kt) {
    const unsigned short* pA = gA + kt * 64;
    const unsigned short* pB = gB + kt * 64;
#pragma unroll
    for (int i = 0; i < 4; ++i) {
      async_copy16(ldsA + i * 1024, pA + (size_t)i * 8 * K);
      async_copy16(ldsB + i * 1024, pB + (size_t)i * 8 * K);
    }
    __syncthreads();
#pragma unroll
    for (int kk = 0; kk < 2; ++kk) {
      const int co = kk ? c1 : c0;
      bf16x8 af[4], bg[4];
#pragma unroll
      for (int mt = 0; mt < 4; ++mt)
        af[mt] = *(const bf16x8*)(fragA + mt * 2048 + co);
#pragma unroll
      for (int nt = 0; nt < 4; ++nt)
        bg[nt] = *(const bf16x8*)(fragB + nt * 2048 + co);
#pragma unroll
      for (int mt = 0; mt < 4; ++mt)
#pragma unroll
        for (int nt = 0; nt < 4; ++nt)
          acc[mt][nt] = __builtin_amdgcn_mfma_f32_16x16x32_bf16(
              af[mt], bg[nt], acc[mt][nt], 0, 0, 0);
    }
    __syncthreads();
  }

  // epilogue: C/D layout col=lane&15, row=quad*4+reg
#pragma unroll
  for (int nt = 0; nt < 4; ++nt) {
    const int n = n0 + wn + nt * 16 + lrow;
    const float bs = bias[n];
#pragma unroll
    for (int mt = 0; mt < 4; ++mt) {
      const int mb = m0 + wm + mt * 16 + quad * 4;
      f32x4 v = acc[mt][nt];
#pragma unroll
      for (int r = 0; r < 4; ++r) {
        float o = v[r] + bs;
        if (MODE == 0) {
          o = fmaxf(o, 0.0f);
          outb[(size_t)(mb + r) * NN + n] = f2bf(o);
        } else {
          outf[(size_t)(mb + r) * NN + n] = o;
        }
      }
    }
  }
}

// ---------------------------------------------------------------------------
// LayerNorm over rows of 1024. One WAVE per row (4 rows/block), shuffle-only
// reduction. grid 4096, block 256.
// ---------------------------------------------------------------------------
__global__ __launch_bounds__(256) void ln_kernel(
    const float* __restrict__ in, const float* __restrict__ lnw,
    const float* __restrict__ lnb, unsigned short* __restrict__ outb,
    float* __restrict__ outf, int wf32) {
  const int wv = threadIdx.x >> 6;
  const int ln = threadIdx.x & 63;
  const int row = blockIdx.x * 4 + wv;
  const float* p = in + (size_t)row * 1024;

  float4 v[4];
  float s = 0.f, q = 0.f;
#pragma unroll
  for (int c = 0; c < 4; ++c) {
    v[c] = *(const float4*)(p + c * 256 + ln * 4);
    s += v[c].x + v[c].y + v[c].z + v[c].w;
    q += v[c].x * v[c].x + v[c].y * v[c].y + v[c].z * v[c].z + v[c].w * v[c].w;
  }
#pragma unroll
  for (int off = 32; off; off >>= 1) {
    s += __shfl_xor(s, off);
    q += __shfl_xor(q, off);
  }
  const float mu  = s * (1.0f / 1024.0f);
  const float var = q * (1.0f / 1024.0f) - mu * mu;
  const float rs  = rsqrtf(var + 1e-5f);

#pragma unroll
  for (int c = 0; c < 4; ++c) {
    const int col = c * 256 + ln * 4;
    const float4 w4 = *(const float4*)(lnw + col);
    const float4 b4 = *(const float4*)(lnb + col);
    const float y0 = (v[c].x - mu) * rs * w4.x + b4.x;
    const float y1 = (v[c].y - mu) * rs * w4.y + b4.y;
    const float y2 = (v[c].z - mu) * rs * w4.z + b4.z;
    const float y3 = (v[c].w - mu) * rs * w4.w + b4.w;
    unsigned short u[4] = {f2bf(y0), f2bf(y1), f2bf(y2), f2bf(y3)};
    *(ushort4*)(outb + (size_t)row * 1024 + col) = *(ushort4*)u;
    if (wf32) {
      float4 y = make_float4(y0, y1, y2, y3);
      *(float4*)(outf + (size_t)row * 1024 + col) = y;
    }
  }
}

// ---------------------------------------------------------------------------
extern "C" void kernel_launch(void* const* d_in, const int* in_sizes, int n_in,
                              void* d_out, int out_size, void* d_ws, size_t ws_size,
                              hipStream_t stream) {
  const float* x    = (const float*)d_in[0];
  const int*   wq   = (const int*)d_in[1];
  const float* wn   = (const float*)d_in[2];
  const float* bias = (const float*)d_in[3];
  const float* la   = (const float*)d_in[4];
  const float* lb   = (const float*)d_in[5];
  const float* lnw  = (const float*)d_in[6];
  const float* lnb  = (const float*)d_in[7];
  float* out = (float*)d_out;

  char* ws = (char*)d_ws;
  unsigned short* Wbf = (unsigned short*)ws;                         // 37.75 MB
  unsigned short* hA  = (unsigned short*)(ws + 37748736);            // 32 MB
  unsigned short* hB  = (unsigned short*)(ws + 37748736 + 33554432); // 32 MB

  dequant_kernel<<<dim3(256, 18), 256, 0, stream>>>(wq, wn, la, lb, Wbf);
  cvt_bf16_kernel<<<4096, 256, 0, stream>>>(x, hA);

  for (int blk = 0; blk < 6; ++blk) {
    const int l = blk * 3;
    gemm_kernel<0><<<1024, 256, 0, stream>>>(
        hA, Wbf + (size_t)l * 1048576, bias + l * 1024, hB, nullptr);
    gemm_kernel<0><<<1024, 256, 0, stream>>>(
        hB, Wbf + (size_t)(l + 1) * 1048576, bias + (l + 1) * 1024, hA, nullptr);
    gemm_kernel<1><<<1024, 256, 0, stream>>>(
        hA, Wbf + (size_t)(l + 2) * 1048576, bias + (l + 2) * 1024, nullptr, out);
    ln_kernel<<<4096, 256, 0, stream>>>(
        out, lnw + blk * 1024, lnb + blk * 1024, hA, out, blk == 5 ? 1 : 0);
  }
}